// Round 4
// baseline (160.343 us; speedup 1.0000x reference)
//
#include <hip/hip_runtime.h>
#include <hip/hip_bf16.h>
#include <stdint.h>

#define N_SAMP 8192
#define D_TOW  128
#define D_HID  128

typedef __bf16 bf16x8 __attribute__((ext_vector_type(8)));
typedef float  f32x4  __attribute__((ext_vector_type(4)));

__device__ __forceinline__ ushort f2bf(float f) {
  union { float f; uint32_t u; } c; c.f = f;
  uint32_t u = c.u;
  return (ushort)((u + 0x7FFFu + ((u >> 16) & 1u)) >> 16);  // RNE
}

// sigmoid via raw HW ops (v_exp_f32 + v_rcp_f32); bias pre-scaled by -log2e.
__device__ __forceinline__ float sig_from_scaled(float acc, float bbc) {
  float e = __builtin_amdgcn_exp2f(__builtin_fmaf(acc, -1.442695040888963f, bbc));
  return __builtin_amdgcn_rcpf(1.0f + e);
}

// fp32 -> bf16 convert for x and W0, fused binary-input check on x.
// Flag protocol: ws is poisoned 0xAA before every launch; we store 1 iff a
// non-{0,1} element exists. towers treats (flag==1) as "not binary".
__global__ __launch_bounds__(256) void prep_kernel(
    const float* __restrict__ x, const float* __restrict__ w0,
    ushort* __restrict__ xb, ushort* __restrict__ w0b, int* __restrict__ flag) {
  const int NX4 = (N_SAMP * D_TOW) / 4;        // 262144
  const int NW4 = (D_TOW * D_HID * D_TOW) / 4; // 524288
  int t = blockIdx.x * blockDim.x + threadIdx.x;
  if (t < NX4) {
    float4 v = ((const float4*)x)[t];
    bool bad = !(((v.x == 0.f) || (v.x == 1.f)) &&
                 ((v.y == 0.f) || (v.y == 1.f)) &&
                 ((v.z == 0.f) || (v.z == 1.f)) &&
                 ((v.w == 0.f) || (v.w == 1.f)));
    ushort4 o;
    o.x = f2bf(v.x); o.y = f2bf(v.y); o.z = f2bf(v.z); o.w = f2bf(v.w);
    ((ushort4*)xb)[t] = o;
    if (__ballot(bad) != 0ull && (threadIdx.x & 63) == 0) *flag = 1;
  } else if (t < NX4 + NW4) {
    int j = t - NX4;
    float4 v = ((const float4*)w0)[j];
    ushort4 o;
    o.x = f2bf(v.x); o.y = f2bf(v.y); o.z = f2bf(v.z); o.w = f2bf(v.w);
    ((ushort4*)w0b)[j] = o;
  }
}

__device__ __forceinline__ void g2l16(const void* g, void* l) {
  __builtin_amdgcn_global_load_lds(
      (const __attribute__((address_space(1))) void*)g,
      (__attribute__((address_space(3))) void*)l, 16, 0, 0);
}

// One block = one tower k x one 128-sample chunk.
// sX staged via g2l (32 KB LDS -> 4 blocks/CU). All 16 W0_k A-fragments are
// loaded to registers BEFORE the staging barrier: the barrier's vmcnt(0)
// drain covers them, so global-A latency is paid once, not per K-step
// (R3's unroll-1 per-step loads were the 77->101 regression).
// bid mapping: xcd=bid&7, kk=(bid>>3)&15, chunk=bid>>7 -> each 64B out line
// (16 consecutive k) written by dispatch-adjacent blocks of one XCD:
// measured WRITE_SIZE 48->4 MB (perfect merge).
__global__ __launch_bounds__(256, 4) void towers_kernel(
    const ushort* __restrict__ xb, const ushort* __restrict__ w0b,
    const float* __restrict__ b0, const float* __restrict__ w1,
    const float* __restrict__ b1, const int* __restrict__ flag,
    float* __restrict__ out) {
  __shared__ __align__(16) ushort sX[128 * 128];  // 32 KB
  __shared__ float sRed[128][2];

  int bid = blockIdx.x;
  int xcd = bid & 7;
  int idx = bid >> 3;
  int kk = idx & 15;
  int chunk = idx >> 4;
  int k = xcd * 16 + kk;
  int n0 = chunk * 128;

  int tid = threadIdx.x;
  int lane = tid & 63;
  int wave = tid >> 6;
  int q = lane >> 4;      // quad index (lane bits 4-5)
  int cl = lane & 15;

  const ushort* xg = xb + n0 * 128;          // [128][128] row-major bf16
  const ushort* wg = w0b + k * (128 * 128);  // W0_k: [h][d] row-major bf16

  int R  = (wave >> 1) * 64;   // n-quadrant
  int Ch = (wave & 1) * 64;    // h-quadrant

  // ---- A-fragments: all 16 global loads issued up front (one latency hit,
  // absorbed by the staging barrier's vmcnt drain). 64 VGPRs.
  const ushort* aRow[4];
#pragma unroll
  for (int f = 0; f < 4; ++f)
    aRow[f] = wg + (Ch + f * 16 + cl) * 128 + q * 8;  // row=h, k-base=q*8

  bf16x8 a[4][4];  // [t][hf]
#pragma unroll
  for (int t = 0; t < 4; ++t)
#pragma unroll
    for (int hf = 0; hf < 4; ++hf)
      a[t][hf] = *(const bf16x8*)(aRow[hf] + t * 32);

  // ---- Stage X tile via g2l. LDS dest = uniform base + lane*16 (HW rule);
  // XOR swizzle on the global source chunk: LDS[row][pos] = g[row][pos^(row&15)].
#pragma unroll
  for (int i = 0; i < 8; ++i) {
    int base = wave * 8192 + i * 1024;       // byte offset, wave-uniform
    int row = wave * 32 + i * 4 + q;
    int c = cl ^ (row & 15);
    g2l16(xg + row * 128 + c * 8, (char*)sX + base);
  }
  __syncthreads();

  f32x4 acc[4][4];             // [hf][nf]
#pragma unroll
  for (int hf = 0; hf < 4; ++hf)
#pragma unroll
    for (int nf = 0; nf < 4; ++nf)
      acc[hf][nf] = (f32x4){0.f, 0.f, 0.f, 0.f};

  int bBase[4];                // X row byte offsets (row = n)
#pragma unroll
  for (int f = 0; f < 4; ++f)
    bBase[f] = (R + f * 16 + cl) * 256;

  // ---- K loop: pure ds_read_b128 + MFMA, fully unrolled.
#pragma unroll
  for (int t = 0; t < 4; ++t) {  // K = 128 = 4 * 32
    bf16x8 b[4];
    int ch = ((t * 4 + q) ^ cl) << 4;        // swizzled 16B chunk offset
#pragma unroll
    for (int nf = 0; nf < 4; ++nf)
      b[nf] = *(const bf16x8*)((const char*)sX + bBase[nf] + ch);
#pragma unroll
    for (int hf = 0; hf < 4; ++hf)
#pragma unroll
      for (int nf = 0; nf < 4; ++nf)
        acc[hf][nf] = __builtin_amdgcn_mfma_f32_16x16x32_bf16(
            a[t][hf], b[nf], acc[hf][nf], 0, 0, 0);
  }

  // Epilogue. C layout: row = h = Ch + hf*16 + q*4 + r ; col = n = R + nf*16 + cl.
  f32x4 bbc[4], wv[4];
#pragma unroll
  for (int hf = 0; hf < 4; ++hf) {
    int h = k * 128 + Ch + hf * 16 + q * 4;
    f32x4 bb = *(const f32x4*)&b0[h];
    wv[hf] = *(const f32x4*)&w1[h];
#pragma unroll
    for (int r = 0; r < 4; ++r)
      bbc[hf][r] = bb[r] * -1.442695040888963f;
  }
  float s[4] = {0.f, 0.f, 0.f, 0.f};
#pragma unroll
  for (int hf = 0; hf < 4; ++hf)
#pragma unroll
    for (int nf = 0; nf < 4; ++nf)
#pragma unroll
      for (int r = 0; r < 4; ++r)
        s[nf] += wv[hf][r] * sig_from_scaled(acc[hf][nf][r], bbc[hf][r]);

#pragma unroll
  for (int m = 16; m <= 32; m <<= 1)
#pragma unroll
    for (int nf = 0; nf < 4; ++nf)
      s[nf] += __shfl_xor(s[nf], m, 64);

  if (q == 0) {
#pragma unroll
    for (int nf = 0; nf < 4; ++nf)
      sRed[R + nf * 16 + cl][wave & 1] = s[nf];
  }
  __syncthreads();

  if (tid < 128) {
    float v = sRed[tid][0] + sRed[tid][1] + b1[k];
    if (*flag != 1) {  // poison(0xAAAAAAAA) or anything-but-1 => binary input
      float e = __builtin_amdgcn_exp2f(v * -1.442695040888963f);
      v = __builtin_amdgcn_rcpf(1.0f + e);
    }
    out[(size_t)(n0 + tid) * D_TOW + k] = v;
  }
}

extern "C" void kernel_launch(void* const* d_in, const int* in_sizes, int n_in,
                              void* d_out, int out_size, void* d_ws, size_t ws_size,
                              hipStream_t stream) {
  const float* x  = (const float*)d_in[0];
  const float* w0 = (const float*)d_in[1];
  const float* b0 = (const float*)d_in[2];
  const float* w1 = (const float*)d_in[3];
  const float* b1 = (const float*)d_in[4];
  float* out = (float*)d_out;

  char* ws = (char*)d_ws;
  int* flag = (int*)ws;
  ushort* xb  = (ushort*)(ws + 1024);                          // 2 MB
  ushort* w0b = (ushort*)(ws + 1024 + N_SAMP * D_TOW * 2);     // 4 MB

  int total4 = (N_SAMP * D_TOW + D_TOW * D_HID * D_TOW) / 4;   // 786432
  prep_kernel<<<total4 / 256, 256, 0, stream>>>(x, w0, xb, w0b, flag);

  towers_kernel<<<8192, 256, 0, stream>>>(xb, w0b, b0, w1, b1, flag, out);
}

// Round 5
// 146.832 us; speedup vs baseline: 1.0920x; 1.0920x over previous
//
#include <hip/hip_runtime.h>
#include <hip/hip_bf16.h>
#include <stdint.h>

#define N_SAMP 8192
#define D_TOW  128
#define D_HID  128
#define LOG2E  1.442695040888963f

typedef __bf16 bf16x8 __attribute__((ext_vector_type(8)));
typedef float  f32x4  __attribute__((ext_vector_type(4)));

__device__ __forceinline__ ushort f2bf(float f) {
  union { float f; uint32_t u; } c; c.f = f;
  uint32_t u = c.u;
  return (ushort)((u + 0x7FFFu + ((u >> 16) & 1u)) >> 16);  // RNE
}

// sigmoid via raw HW ops (v_exp_f32 + v_rcp_f32); bias pre-scaled by -log2e.
__device__ __forceinline__ float sig_from_scaled(float acc, float bbc) {
  float e = __builtin_amdgcn_exp2f(__builtin_fmaf(acc, -LOG2E, bbc));
  return __builtin_amdgcn_rcpf(1.0f + e);
}

// fp32 -> bf16 convert for x and W0, fused binary-input check on x.
// Flag protocol: ws is poisoned 0xAA before every launch; we store 1 iff a
// non-{0,1} element exists. towers treats (flag==1) as "not binary".
__global__ __launch_bounds__(256) void prep_kernel(
    const float* __restrict__ x, const float* __restrict__ w0,
    ushort* __restrict__ xb, ushort* __restrict__ w0b, int* __restrict__ flag) {
  const int NX4 = (N_SAMP * D_TOW) / 4;        // 262144
  const int NW4 = (D_TOW * D_HID * D_TOW) / 4; // 524288
  int t = blockIdx.x * blockDim.x + threadIdx.x;
  if (t < NX4) {
    float4 v = ((const float4*)x)[t];
    bool bad = !(((v.x == 0.f) || (v.x == 1.f)) &&
                 ((v.y == 0.f) || (v.y == 1.f)) &&
                 ((v.z == 0.f) || (v.z == 1.f)) &&
                 ((v.w == 0.f) || (v.w == 1.f)));
    ushort4 o;
    o.x = f2bf(v.x); o.y = f2bf(v.y); o.z = f2bf(v.z); o.w = f2bf(v.w);
    ((ushort4*)xb)[t] = o;
    if (__ballot(bad) != 0ull && (threadIdx.x & 63) == 0) *flag = 1;
  } else if (t < NX4 + NW4) {
    int j = t - NX4;
    float4 v = ((const float4*)w0)[j];
    ushort4 o;
    o.x = f2bf(v.x); o.y = f2bf(v.y); o.z = f2bf(v.z); o.w = f2bf(v.w);
    ((ushort4*)w0b)[j] = o;
  }
}

__device__ __forceinline__ void g2l16(const void* g, void* l) {
  __builtin_amdgcn_global_load_lds(
      (const __attribute__((address_space(1))) void*)g,
      (__attribute__((address_space(3))) void*)l, 16, 0, 0);
}

// One block = 4 towers (k0..k0+3) x one 128-sample chunk.
//  - X tile staged once to LDS (32 KB, 0-conflict XOR swizzle, g2l width 16).
//  - W0 A-fragments in REGISTERS, gathered from L2; next tower's 16 loads
//    are interleaved into the current tower's MFMA loop (manual SWP).
//    Peak regs ~233 < 256 (launch_bounds(256,2)) -- R4's spill trap avoided.
//  - No barriers between towers: per-wave phase drift lets sigmoid VALU of
//    one wave overlap MFMA of another.
//  - Output: one float4 per sample row (4 consecutive k) -> full 64B-line
//    merge inside the block.
__global__ __launch_bounds__(256, 2) void towers_kernel(
    const ushort* __restrict__ xb, const ushort* __restrict__ w0b,
    const float* __restrict__ b0, const float* __restrict__ w1,
    const float* __restrict__ b1, const int* __restrict__ flag,
    float* __restrict__ out) {
  __shared__ __align__(16) ushort sX[128 * 128];  // 32 KB
  __shared__ float sRed[4][128][2];               // 4 KB

  int bid = blockIdx.x;
  int xcd = bid & 7;             // XCD locality: towers k0 = xcd*16 + kg*4
  int r = bid >> 3;
  int kg = r & 3;
  int chunk = r >> 2;
  int k0 = xcd * 16 + kg * 4;
  int n0 = chunk * 128;

  int tid = threadIdx.x;
  int lane = tid & 63;
  int wave = tid >> 6;
  int q = lane >> 4;             // lane bits 4-5
  int cl = lane & 15;

  const ushort* xg = xb + n0 * 128;                 // [128][128] bf16
  const ushort* wg = w0b + k0 * (128 * 128);        // 4 towers' W0, contiguous

  int R  = (wave >> 1) * 64;     // n-quadrant
  int Ch = (wave & 1) * 64;      // h-quadrant

  // A-fragment element offsets within one tower's W0 (row = h, k-chunk q*8).
  int aOff[4];
#pragma unroll
  for (int f = 0; f < 4; ++f)
    aOff[f] = (Ch + f * 16 + cl) * 128 + q * 8;

  // Tower-0 A-fragments issued before staging: the barrier's vmcnt drain
  // absorbs their latency.
  bf16x8 aC[4][4];  // [t][hf]
#pragma unroll
  for (int t = 0; t < 4; ++t)
#pragma unroll
    for (int hf = 0; hf < 4; ++hf)
      aC[t][hf] = *(const bf16x8*)(wg + aOff[hf] + t * 32);

  // Stage X via g2l (LDS dest = uniform base + lane*16; XOR swizzle on the
  // global source chunk: LDS[row][pos] = g[row][pos^(row&15)]).
#pragma unroll
  for (int i = 0; i < 8; ++i) {
    int base = wave * 8192 + i * 1024;
    int row = wave * 32 + i * 4 + q;
    int c = cl ^ (row & 15);
    g2l16(xg + row * 128 + c * 8, (char*)sX + base);
  }
  __syncthreads();

  int bBase[4];                  // X row byte offsets (row = n)
#pragma unroll
  for (int f = 0; f < 4; ++f)
    bBase[f] = (R + f * 16 + cl) * 256;

  int flagv = *flag;

#pragma unroll
  for (int j = 0; j < 4; ++j) {  // towers, fully unrolled (SSA renames aC/aN)
    int k = k0 + j;

    f32x4 acc[4][4];             // [hf][nf]
#pragma unroll
    for (int hf = 0; hf < 4; ++hf)
#pragma unroll
      for (int nf = 0; nf < 4; ++nf)
        acc[hf][nf] = (f32x4){0.f, 0.f, 0.f, 0.f};

    bf16x8 aN[4][4];
    const ushort* wgn = wg + (j + 1) * (128 * 128);

#pragma unroll
    for (int t = 0; t < 4; ++t) {  // K = 128 = 4 * 32
      bf16x8 b[4];
      int ch = ((t * 4 + q) ^ cl) << 4;
#pragma unroll
      for (int nf = 0; nf < 4; ++nf)
        b[nf] = *(const bf16x8*)((const char*)sX + bBase[nf] + ch);
      // prefetch next tower's A-frags for this t (hidden under MFMA+epilogue)
      if (j < 3) {
#pragma unroll
        for (int hf = 0; hf < 4; ++hf)
          aN[t][hf] = *(const bf16x8*)(wgn + aOff[hf] + t * 32);
      }
#pragma unroll
      for (int hf = 0; hf < 4; ++hf)
#pragma unroll
        for (int nf = 0; nf < 4; ++nf)
          acc[hf][nf] = __builtin_amdgcn_mfma_f32_16x16x32_bf16(
              aC[t][hf], b[nf], acc[hf][nf], 0, 0, 0);
    }

    // Epilogue. C layout: row=h=Ch+hf*16+q*4+r ; col=n=R+nf*16+cl.
    f32x4 bbc[4], wv[4];
#pragma unroll
    for (int hf = 0; hf < 4; ++hf) {
      int h = k * 128 + Ch + hf * 16 + q * 4;
      f32x4 bb = *(const f32x4*)&b0[h];
      wv[hf] = *(const f32x4*)&w1[h];
#pragma unroll
      for (int rr = 0; rr < 4; ++rr)
        bbc[hf][rr] = bb[rr] * -LOG2E;
    }
    float s[4] = {0.f, 0.f, 0.f, 0.f};
#pragma unroll
    for (int hf = 0; hf < 4; ++hf)
#pragma unroll
      for (int nf = 0; nf < 4; ++nf)
#pragma unroll
        for (int rr = 0; rr < 4; ++rr)
          s[nf] += wv[hf][rr] * sig_from_scaled(acc[hf][nf][rr], bbc[hf][rr]);

#pragma unroll
    for (int m = 16; m <= 32; m <<= 1)
#pragma unroll
      for (int nf = 0; nf < 4; ++nf)
        s[nf] += __shfl_xor(s[nf], m, 64);

    if (q == 0) {
#pragma unroll
      for (int nf = 0; nf < 4; ++nf)
        sRed[j][R + nf * 16 + cl][wave & 1] = s[nf];
    }

    if (j < 3) {
#pragma unroll
      for (int t = 0; t < 4; ++t)
#pragma unroll
        for (int hf = 0; hf < 4; ++hf)
          aC[t][hf] = aN[t][hf];
    }
  }
  __syncthreads();

  if (tid < 128) {
    f32x4 o;
#pragma unroll
    for (int j = 0; j < 4; ++j) {
      float v = sRed[j][tid][0] + sRed[j][tid][1] + b1[k0 + j];
      if (flagv != 1) {  // poison(0xAAAAAAAA) or anything-but-1 => binary
        float e = __builtin_amdgcn_exp2f(v * -LOG2E);
        v = __builtin_amdgcn_rcpf(1.0f + e);
      }
      o[j] = v;
    }
    *(f32x4*)&out[(size_t)(n0 + tid) * D_TOW + k0] = o;  // 16B, k0%4==0
  }
}

extern "C" void kernel_launch(void* const* d_in, const int* in_sizes, int n_in,
                              void* d_out, int out_size, void* d_ws, size_t ws_size,
                              hipStream_t stream) {
  const float* x  = (const float*)d_in[0];
  const float* w0 = (const float*)d_in[1];
  const float* b0 = (const float*)d_in[2];
  const float* w1 = (const float*)d_in[3];
  const float* b1 = (const float*)d_in[4];
  float* out = (float*)d_out;

  char* ws = (char*)d_ws;
  int* flag = (int*)ws;
  ushort* xb  = (ushort*)(ws + 1024);                          // 2 MB
  ushort* w0b = (ushort*)(ws + 1024 + N_SAMP * D_TOW * 2);     // 4 MB

  int total4 = (N_SAMP * D_TOW + D_TOW * D_HID * D_TOW) / 4;   // 786432
  prep_kernel<<<total4 / 256, 256, 0, stream>>>(x, w0, xb, w0b, flag);

  towers_kernel<<<2048, 256, 0, stream>>>(xb, w0b, b0, w1, b1, flag, out);
}

// Round 6
// 145.184 us; speedup vs baseline: 1.1044x; 1.0114x over previous
//
#include <hip/hip_runtime.h>
#include <hip/hip_bf16.h>
#include <stdint.h>

#define N_SAMP 8192
#define D_TOW  128
#define D_HID  128
#define LOG2E  1.442695040888963f

typedef __bf16 bf16x8 __attribute__((ext_vector_type(8)));
typedef float  f32x4  __attribute__((ext_vector_type(4)));

__device__ __forceinline__ ushort f2bf(float f) {
  union { float f; uint32_t u; } c; c.f = f;
  uint32_t u = c.u;
  return (ushort)((u + 0x7FFFu + ((u >> 16) & 1u)) >> 16);  // RNE
}

// fp32 -> bf16 convert for x and W0, fused binary-input check on x.
// Flag protocol: ws is poisoned 0xAA before every launch; we store 1 iff a
// non-{0,1} element exists. towers treats (flag==1) as "not binary".
__global__ __launch_bounds__(256) void prep_kernel(
    const float* __restrict__ x, const float* __restrict__ w0,
    ushort* __restrict__ xb, ushort* __restrict__ w0b, int* __restrict__ flag) {
  const int NX4 = (N_SAMP * D_TOW) / 4;        // 262144
  const int NW4 = (D_TOW * D_HID * D_TOW) / 4; // 524288
  int t = blockIdx.x * blockDim.x + threadIdx.x;
  if (t < NX4) {
    float4 v = ((const float4*)x)[t];
    bool bad = !(((v.x == 0.f) || (v.x == 1.f)) &&
                 ((v.y == 0.f) || (v.y == 1.f)) &&
                 ((v.z == 0.f) || (v.z == 1.f)) &&
                 ((v.w == 0.f) || (v.w == 1.f)));
    ushort4 o;
    o.x = f2bf(v.x); o.y = f2bf(v.y); o.z = f2bf(v.z); o.w = f2bf(v.w);
    ((ushort4*)xb)[t] = o;
    if (__ballot(bad) != 0ull && (threadIdx.x & 63) == 0) *flag = 1;
  } else if (t < NX4 + NW4) {
    int j = t - NX4;
    float4 v = ((const float4*)w0)[j];
    ushort4 o;
    o.x = f2bf(v.x); o.y = f2bf(v.y); o.z = f2bf(v.z); o.w = f2bf(v.w);
    ((ushort4*)w0b)[j] = o;
  }
}

__device__ __forceinline__ void g2l16(const void* g, void* l) {
  __builtin_amdgcn_global_load_lds(
      (const __attribute__((address_space(1))) void*)g,
      (__attribute__((address_space(3))) void*)l, 16, 0, 0);
}

// One block = 256 threads (1 wave/SIMD) = 64 samples x 4 towers.
// Wave tile: 64n x 32h (acc = 8 frags = 32 AGPR).
//  - X tile 64x128 staged once to LDS (16 KB, 0-conflict XOR swizzle).
//  - b-frags (X side) are TOWER-INVARIANT: 16 frags = 64 VGPR, read from LDS
//    once, reused by all 4 towers -> the t-loop is a pure 32-MFMA burst with
//    no LDS reads/waits inside.
//  - W0 A-frags (8 per tower) prefetched one tower ahead; the previous
//    tower's ~800-cyc epilogue covers L2 latency.
//  - Reduce via fire-and-forget LDS partials (17-padded: <=2-way banks, free)
//    instead of dependent shfl_xor chains.
//  - bid map keeps 16 consecutive k per XCD and kgroup-adjacent dispatch ->
//    measured-perfect 4 MB WRITE_SIZE.
__global__ __launch_bounds__(256, 3) void towers_kernel(
    const ushort* __restrict__ xb, const ushort* __restrict__ w0b,
    const float* __restrict__ b0, const float* __restrict__ w1,
    const float* __restrict__ b1, const int* __restrict__ flag,
    float* __restrict__ out) {
  __shared__ __align__(16) ushort sX[64 * 128];  // 16 KB
  __shared__ float sG[4][64][17];                // 17.4 KB, pad 17 (coprime 32)

  int bid = blockIdx.x;
  int xcd = bid & 7;
  int r = bid >> 3;
  int kg4 = r & 3;
  int chunk = r >> 2;                // 0..127
  int k0 = xcd * 16 + kg4 * 4;
  int n0 = chunk * 64;

  int tid = threadIdx.x;
  int lane = tid & 63;
  int wave = tid >> 6;
  int q = lane >> 4;                 // lane bits 4-5
  int cl = lane & 15;

  const ushort* xg = xb + n0 * 128;          // [64][128] bf16 rows
  const ushort* wg = w0b + k0 * (128 * 128); // 4 towers' W0, contiguous

  // A-frag offsets within one tower (row = h = wave*32 + f*16 + cl).
  int aOff[2];
#pragma unroll
  for (int f = 0; f < 2; ++f)
    aOff[f] = (wave * 32 + f * 16 + cl) * 128 + q * 8;

  // Tower-0 A prefetch: issued before the staging barrier (vmcnt drain covers).
  bf16x8 aA[4][2], aB[4][2];
#pragma unroll
  for (int t = 0; t < 4; ++t)
#pragma unroll
    for (int f = 0; f < 2; ++f)
      aA[t][f] = *(const bf16x8*)(wg + aOff[f] + t * 32);

  // Stage X (16 KB): 4 g2l iters/wave. LDS dest = uniform base + lane*16;
  // XOR swizzle on the global source chunk: LDS[row][pos] = g[row][pos^(row&15)].
#pragma unroll
  for (int i = 0; i < 4; ++i) {
    int base = wave * 4096 + i * 1024;
    int row = wave * 16 + i * 4 + q;
    int c = cl ^ (row & 15);
    g2l16(xg + row * 128 + c * 8, (char*)sX + base);
  }
  __syncthreads();

  int flagv = *flag;

  // Tower-invariant b-frags: B[k][n], lane holds X[n = nf*16+cl][d-chunk t*4+q].
  bf16x8 b[4][4];  // [t][nf] = 64 VGPR
#pragma unroll
  for (int t = 0; t < 4; ++t)
#pragma unroll
    for (int nf = 0; nf < 4; ++nf)
      b[t][nf] = *(const bf16x8*)(
          (const char*)sX + (nf * 16 + cl) * 256 + (((t * 4 + q) ^ cl) << 4));

  // Per-tower body: 32-MFMA burst, prefetch next tower's A, sigmoid epilogue,
  // partial write. ACUR/ANEXT ping-pong via macro (keeps arrays in registers).
#define TOWER_BODY(J, ACUR, ANEXT, DO_PRE)                                     \
  {                                                                            \
    f32x4 acc[2][4];                                                           \
    _Pragma("unroll") for (int hf = 0; hf < 2; ++hf)                           \
        _Pragma("unroll") for (int nf = 0; nf < 4; ++nf)                       \
            acc[hf][nf] = (f32x4){0.f, 0.f, 0.f, 0.f};                         \
    _Pragma("unroll") for (int t = 0; t < 4; ++t)                              \
        _Pragma("unroll") for (int hf = 0; hf < 2; ++hf)                       \
            _Pragma("unroll") for (int nf = 0; nf < 4; ++nf)                   \
                acc[hf][nf] = __builtin_amdgcn_mfma_f32_16x16x32_bf16(         \
                    ACUR[t][hf], b[t][nf], acc[hf][nf], 0, 0, 0);              \
    if (DO_PRE) {                                                              \
      const ushort* wgn = wg + (J + 1) * (128 * 128);                          \
      _Pragma("unroll") for (int t = 0; t < 4; ++t)                            \
          _Pragma("unroll") for (int f = 0; f < 2; ++f)                        \
              ANEXT[t][f] = *(const bf16x8*)(wgn + aOff[f] + t * 32);          \
    }                                                                          \
    float s[4] = {0.f, 0.f, 0.f, 0.f};                                         \
    _Pragma("unroll") for (int hf = 0; hf < 2; ++hf) {                         \
      int h = (k0 + J) * 128 + wave * 32 + hf * 16 + q * 4;                    \
      f32x4 bb = *(const f32x4*)&b0[h];                                        \
      f32x4 wv = *(const f32x4*)&w1[h];                                        \
      f32x4 bbc;                                                               \
      _Pragma("unroll") for (int rr = 0; rr < 4; ++rr)                         \
          bbc[rr] = bb[rr] * -LOG2E;                                           \
      _Pragma("unroll") for (int nf = 0; nf < 4; ++nf)                         \
          _Pragma("unroll") for (int rr = 0; rr < 4; ++rr) {                   \
        float e = __builtin_amdgcn_exp2f(                                      \
            __builtin_fmaf(acc[hf][nf][rr], -LOG2E, bbc[rr]));                 \
        s[nf] = __builtin_fmaf(wv[rr], __builtin_amdgcn_rcpf(1.0f + e), s[nf]);\
      }                                                                        \
    }                                                                          \
    _Pragma("unroll") for (int nf = 0; nf < 4; ++nf)                           \
        sG[J][nf * 16 + cl][wave * 4 + q] = s[nf];                             \
  }

  TOWER_BODY(0, aA, aB, 1)
  TOWER_BODY(1, aB, aA, 1)
  TOWER_BODY(2, aA, aB, 1)
  TOWER_BODY(3, aB, aA, 0)
#undef TOWER_BODY

  __syncthreads();

  // Final pass: one thread per (n, j): sum 16 partials + b1, optional sigmoid.
  {
    int n = tid & 63;
    int j = tid >> 6;
    float v = b1[k0 + j];
#pragma unroll
    for (int p = 0; p < 16; ++p)
      v += sG[j][n][p];
    if (flagv != 1) {  // poison(0xAAAAAAAA) or anything-but-1 => binary input
      float e = __builtin_amdgcn_exp2f(v * -LOG2E);
      v = __builtin_amdgcn_rcpf(1.0f + e);
    }
    out[(size_t)(n0 + n) * D_TOW + k0 + j] = v;
  }
}

extern "C" void kernel_launch(void* const* d_in, const int* in_sizes, int n_in,
                              void* d_out, int out_size, void* d_ws, size_t ws_size,
                              hipStream_t stream) {
  const float* x  = (const float*)d_in[0];
  const float* w0 = (const float*)d_in[1];
  const float* b0 = (const float*)d_in[2];
  const float* w1 = (const float*)d_in[3];
  const float* b1 = (const float*)d_in[4];
  float* out = (float*)d_out;

  char* ws = (char*)d_ws;
  int* flag = (int*)ws;
  ushort* xb  = (ushort*)(ws + 1024);                          // 2 MB
  ushort* w0b = (ushort*)(ws + 1024 + N_SAMP * D_TOW * 2);     // 4 MB

  int total4 = (N_SAMP * D_TOW + D_TOW * D_HID * D_TOW) / 4;   // 786432
  prep_kernel<<<total4 / 256, 256, 0, stream>>>(x, w0, xb, w0b, flag);

  towers_kernel<<<4096, 256, 0, stream>>>(xb, w0b, b0, w1, b1, flag, out);
}

// Round 7
// 145.137 us; speedup vs baseline: 1.1048x; 1.0003x over previous
//
#include <hip/hip_runtime.h>
#include <hip/hip_bf16.h>
#include <stdint.h>

#define N_SAMP 8192
#define D_TOW  128
#define D_HID  128
#define LOG2E  1.442695040888963f

typedef __bf16 bf16x8 __attribute__((ext_vector_type(8)));
typedef float  f32x4  __attribute__((ext_vector_type(4)));

__device__ __forceinline__ ushort f2bf(float f) {
  union { float f; uint32_t u; } c; c.f = f;
  uint32_t u = c.u;
  return (ushort)((u + 0x7FFFu + ((u >> 16) & 1u)) >> 16);  // RNE
}

// fp32 -> bf16 convert for x and W0, fused binary-input check on x.
// Flag protocol: ws is poisoned 0xAA before every launch; we store 1 iff a
// non-{0,1} element exists. towers treats (flag==1) as "not binary".
__global__ __launch_bounds__(256) void prep_kernel(
    const float* __restrict__ x, const float* __restrict__ w0,
    ushort* __restrict__ xb, ushort* __restrict__ w0b, int* __restrict__ flag) {
  const int NX4 = (N_SAMP * D_TOW) / 4;        // 262144
  const int NW4 = (D_TOW * D_HID * D_TOW) / 4; // 524288
  int t = blockIdx.x * blockDim.x + threadIdx.x;
  if (t < NX4) {
    float4 v = ((const float4*)x)[t];
    bool bad = !(((v.x == 0.f) || (v.x == 1.f)) &&
                 ((v.y == 0.f) || (v.y == 1.f)) &&
                 ((v.z == 0.f) || (v.z == 1.f)) &&
                 ((v.w == 0.f) || (v.w == 1.f)));
    ushort4 o;
    o.x = f2bf(v.x); o.y = f2bf(v.y); o.z = f2bf(v.z); o.w = f2bf(v.w);
    ((ushort4*)xb)[t] = o;
    if (__ballot(bad) != 0ull && (threadIdx.x & 63) == 0) *flag = 1;
  } else if (t < NX4 + NW4) {
    int j = t - NX4;
    float4 v = ((const float4*)w0)[j];
    ushort4 o;
    o.x = f2bf(v.x); o.y = f2bf(v.y); o.z = f2bf(v.z); o.w = f2bf(v.w);
    ((ushort4*)w0b)[j] = o;
  }
}

__device__ __forceinline__ void g2l16(const void* g, void* l) {
  __builtin_amdgcn_global_load_lds(
      (const __attribute__((address_space(1))) void*)g,
      (__attribute__((address_space(3))) void*)l, 16, 0, 0);
}

// One block = 256 threads = 64 samples x 4 towers; wave tile 64n x 32h.
// INTRA-WAVE SOFTWARE PIPELINE across towers (acc double-buffer):
//   PREF(0) | stage | PREF(1) | B(0) B(1) | PREF(2) E(0) | B(2) | PREF(3)
//   E(1) | B(3) | E(2) E(3)
// Burst(j+1) issues (~160 cyc) BEFORE epilogue(j) (~750 cyc VALU), so MFMA
// executes in the background of the sigmoid VALU and A-prefetch L2 latency
// is covered by the preceding epilogue. b-frags come from LDS per burst
// (R5's 0-conflict XOR pattern) to keep registers ~<200 (no R4-style spill:
// watch WRITE_SIZE == 4096 KB).
__global__ __launch_bounds__(256, 2) void towers_kernel(
    const ushort* __restrict__ xb, const ushort* __restrict__ w0b,
    const float* __restrict__ b0, const float* __restrict__ w1,
    const float* __restrict__ b1, const int* __restrict__ flag,
    float* __restrict__ out) {
  __shared__ __align__(16) ushort sX[64 * 128];  // 16 KB
  __shared__ float sG[4][64][17];                // 17.4 KB, pad 17 vs 32 banks

  int bid = blockIdx.x;
  int xcd = bid & 7;
  int r = bid >> 3;
  int kg4 = r & 3;
  int chunk = r >> 2;                // 0..127
  int k0 = xcd * 16 + kg4 * 4;
  int n0 = chunk * 64;

  int tid = threadIdx.x;
  int lane = tid & 63;
  int wave = tid >> 6;
  int q = lane >> 4;                 // lane bits 4-5
  int cl = lane & 15;

  const ushort* xg = xb + n0 * 128;          // [64][128] bf16 rows
  const ushort* wg = w0b + k0 * (128 * 128); // 4 towers' W0, contiguous

  // A-frag offsets within one tower (row = h = wave*32 + f*16 + cl).
  int aOff[2];
#pragma unroll
  for (int f = 0; f < 2; ++f)
    aOff[f] = (wave * 32 + f * 16 + cl) * 128 + q * 8;

  bf16x8 aA[4][2], aB[4][2];
  f32x4 acc0[2][4], acc1[2][4];

#define PREF(J, AFR)                                                           \
  do {                                                                         \
    const ushort* wp = wg + (J) * (128 * 128);                                 \
    _Pragma("unroll") for (int t = 0; t < 4; ++t)                              \
        _Pragma("unroll") for (int f = 0; f < 2; ++f)                          \
            AFR[t][f] = *(const bf16x8*)(wp + aOff[f] + t * 32);               \
  } while (0)

#define BURST(ACC, AFR)                                                        \
  do {                                                                         \
    _Pragma("unroll") for (int hf = 0; hf < 2; ++hf)                           \
        _Pragma("unroll") for (int nf = 0; nf < 4; ++nf)                       \
            ACC[hf][nf] = (f32x4){0.f, 0.f, 0.f, 0.f};                         \
    _Pragma("unroll") for (int t = 0; t < 4; ++t) {                            \
      bf16x8 bfr[4];                                                           \
      int ch = ((t * 4 + q) ^ cl) << 4;                                        \
      _Pragma("unroll") for (int nf = 0; nf < 4; ++nf)                         \
          bfr[nf] = *(const bf16x8*)(                                          \
              (const char*)sX + (nf * 16 + cl) * 256 + ch);                    \
      _Pragma("unroll") for (int hf = 0; hf < 2; ++hf)                         \
          _Pragma("unroll") for (int nf = 0; nf < 4; ++nf)                     \
              ACC[hf][nf] = __builtin_amdgcn_mfma_f32_16x16x32_bf16(           \
                  AFR[t][hf], bfr[nf], ACC[hf][nf], 0, 0, 0);                  \
    }                                                                          \
  } while (0)

#define EPI(J, ACC)                                                            \
  do {                                                                         \
    float s[4] = {0.f, 0.f, 0.f, 0.f};                                         \
    _Pragma("unroll") for (int hf = 0; hf < 2; ++hf) {                         \
      int h = (k0 + (J)) * 128 + wave * 32 + hf * 16 + q * 4;                  \
      f32x4 bb = *(const f32x4*)&b0[h];                                        \
      f32x4 wv = *(const f32x4*)&w1[h];                                        \
      _Pragma("unroll") for (int nf = 0; nf < 4; ++nf)                         \
          _Pragma("unroll") for (int rr = 0; rr < 4; ++rr) {                   \
        float e = __builtin_amdgcn_exp2f(__builtin_fmaf(                       \
            ACC[hf][nf][rr] + bb[rr], -LOG2E, 0.f));                           \
        s[nf] = __builtin_fmaf(wv[rr], __builtin_amdgcn_rcpf(1.0f + e), s[nf]);\
      }                                                                        \
    }                                                                          \
    _Pragma("unroll") for (int nf = 0; nf < 4; ++nf)                           \
        sG[J][nf * 16 + cl][wave * 4 + q] = s[nf];                             \
  } while (0)

  // Tower-0 A prefetch before staging (barrier vmcnt drain covers it).
  PREF(0, aA);

  // Stage X (16 KB) via g2l; XOR swizzle on the global source chunk:
  // LDS[row][pos] = g[row][pos^(row&15)].
#pragma unroll
  for (int i = 0; i < 4; ++i) {
    int base = wave * 4096 + i * 1024;
    int row = wave * 16 + i * 4 + q;
    int c = cl ^ (row & 15);
    g2l16(xg + row * 128 + c * 8, (char*)sX + base);
  }
  __syncthreads();

  int flagv = *flag;

  PREF(1, aB);
  BURST(acc0, aA);      // tower 0
  BURST(acc1, aB);      // tower 1 -- executes under epilogue(0)
  PREF(2, aA);          // L2 latency covered by epilogue(0)
  EPI(0, acc0);
  BURST(acc0, aA);      // tower 2 -- under epilogue(1)
  PREF(3, aB);
  EPI(1, acc1);
  BURST(acc1, aB);      // tower 3 -- under epilogue(2)
  EPI(2, acc0);
  EPI(3, acc1);

#undef PREF
#undef BURST
#undef EPI

  __syncthreads();

  // Final pass: one thread per (n, j): sum 16 partials + b1, optional sigmoid.
  {
    int n = tid & 63;
    int j = tid >> 6;
    float v = b1[k0 + j];
#pragma unroll
    for (int p = 0; p < 16; ++p)
      v += sG[j][n][p];
    if (flagv != 1) {  // poison(0xAAAAAAAA) or anything-but-1 => binary input
      float e = __builtin_amdgcn_exp2f(v * -LOG2E);
      v = __builtin_amdgcn_rcpf(1.0f + e);
    }
    out[(size_t)(n0 + n) * D_TOW + k0 + j] = v;
  }
}

extern "C" void kernel_launch(void* const* d_in, const int* in_sizes, int n_in,
                              void* d_out, int out_size, void* d_ws, size_t ws_size,
                              hipStream_t stream) {
  const float* x  = (const float*)d_in[0];
  const float* w0 = (const float*)d_in[1];
  const float* b0 = (const float*)d_in[2];
  const float* w1 = (const float*)d_in[3];
  const float* b1 = (const float*)d_in[4];
  float* out = (float*)d_out;

  char* ws = (char*)d_ws;
  int* flag = (int*)ws;
  ushort* xb  = (ushort*)(ws + 1024);                          // 2 MB
  ushort* w0b = (ushort*)(ws + 1024 + N_SAMP * D_TOW * 2);     // 4 MB

  int total4 = (N_SAMP * D_TOW + D_TOW * D_HID * D_TOW) / 4;   // 786432
  prep_kernel<<<total4 / 256, 256, 0, stream>>>(x, w0, xb, w0b, flag);

  towers_kernel<<<4096, 256, 0, stream>>>(xb, w0b, b0, w1, b1, flag, out);
}